// Round 7
// baseline (52.618 us; speedup 1.0000x reference)
//
#include <hip/hip_runtime.h>
#include <math.h>

#define B 64
#define K 16
#define J 512
#define I 128
#define SCALE 0.08838834764831845f /* 1/sqrt(128) */
#define EPSF 1e-20f
#define JC 16  /* j-chunks */
#define JCW 32 /* J / JC */

typedef __attribute__((ext_vector_type(8))) short short8;
typedef __attribute__((ext_vector_type(4))) float f32x4;

static __device__ __forceinline__ unsigned f2bf(float f) {
    union { float f; unsigned u; } v; v.f = f;
    return (v.u + 0x7FFFu + ((v.u >> 16) & 1u)) >> 16;  // RNE to bf16
}

// ---------------------------------------------------------------------------
// K1: logits via bf16 MFMA + softmax over batch + bias.
// 256 threads per block: all 4 waves cooperatively stage x^2/w^2 (4x load
// parallelism vs 1-wave), wave 0 does the 16 MFMAs + in-register softmax.
// XCD-aligned j (XCD c owns j in [64c,64c+64)) pre-warms k3's L2 slice.
// Output blocked cw2[kt(4)][bt(8)][j(512)][kk(4)*8+bb(8)] for k3 staging.
// ---------------------------------------------------------------------------
__global__ __launch_bounds__(256) void k1_mfma(const float* __restrict__ x,
                                               const float* __restrict__ w,
                                               const float* __restrict__ bias,
                                               float* __restrict__ cw2) {
    __shared__ __align__(16) char lds[80 * 256];  // lx[64][256] + lw[16][256]
    char* lx = lds;
    char* lw = lds + 64 * 256;

    const int raw = blockIdx.x;                  // 0..511
    const int j = (raw & 7) * 64 + (raw >> 3);   // XCD-aligned j
    const int tid = threadIdx.x;

#pragma unroll
    for (int r = 0; r < 8; ++r) {
        int item = tid + 256 * r;                // 0..2047
        int row = item >> 5, q = item & 31;
        float4 v = *(const float4*)(x + ((size_t)row * J + j) * I + q * 4);
        uint2 u;
        u.x = f2bf(v.x * v.x) | (f2bf(v.y * v.y) << 16);
        u.y = f2bf(v.z * v.z) | (f2bf(v.w * v.w) << 16);
        *(uint2*)(lx + row * 256 + ((q * 8) ^ ((row & 7) << 4))) = u;
    }
#pragma unroll
    for (int r = 0; r < 2; ++r) {
        int item = tid + 256 * r;                // 0..511
        int k = item >> 5, q = item & 31;
        float4 v = *(const float4*)(w + ((size_t)k * J + j) * I + q * 4);
        uint2 u;
        u.x = f2bf(v.x * v.x) | (f2bf(v.y * v.y) << 16);
        u.y = f2bf(v.z * v.z) | (f2bf(v.w * v.w) << 16);
        *(uint2*)(lw + k * 256 + ((q * 8) ^ ((k & 7) << 4))) = u;
    }
    __syncthreads();
    if (tid >= 64) return;

    const int g = tid >> 4, n = tid & 15;
    f32x4 acc[4];
#pragma unroll
    for (int t = 0; t < 4; ++t) acc[t] = (f32x4){0.f, 0.f, 0.f, 0.f};

#pragma unroll
    for (int s = 0; s < 4; ++s) {
        const int colb = s * 64 + g * 16;
        short8 af = *(const short8*)(lw + n * 256 + (colb ^ ((n & 7) << 4)));
#pragma unroll
        for (int t = 0; t < 4; ++t) {
            int row = t * 16 + n;
            short8 bf = *(const short8*)(lx + row * 256 + (colb ^ ((row & 7) << 4)));
            acc[t] = __builtin_amdgcn_mfma_f32_16x16x32_bf16(af, bf, acc[t], 0, 0, 0);
        }
    }

    // lane holds c_raw[m=g*4+r][b=t*16+n] in acc[t][r]
#pragma unroll
    for (int r = 0; r < 4; ++r) {
        float s0 = acc[0][r] * SCALE, s1 = acc[1][r] * SCALE;
        float s2 = acc[2][r] * SCALE, s3 = acc[3][r] * SCALE;
        float mx = fmaxf(fmaxf(s0, s1), fmaxf(s2, s3));
#pragma unroll
        for (int msk = 1; msk <= 8; msk <<= 1) mx = fmaxf(mx, __shfl_xor(mx, msk, 64));
        float e0 = expf(s0 - mx), e1 = expf(s1 - mx);
        float e2 = expf(s2 - mx), e3 = expf(s3 - mx);
        float sum = e0 + e1 + e2 + e3;
#pragma unroll
        for (int msk = 1; msk <= 8; msk <<= 1) sum += __shfl_xor(sum, msk, 64);
        float inv = 1.f / sum;
        float bi = bias[(g * 4 + r) * J + j];
        // cw2[kt=g][bt=t*2+(n>>3)][j][kk=r][bb=n&7]
        size_t base = (((size_t)g * 8) * 512 + j) * 32 + r * 8 + (n & 7);
        size_t btoff = (size_t)(n >> 3) * 512 * 32;
        cw2[base + btoff + (size_t)0 * 2 * 512 * 32] = e0 * inv + bi;
        cw2[base + btoff + (size_t)1 * 2 * 512 * 32] = e1 * inv + bi;
        cw2[base + btoff + (size_t)2 * 2 * 512 * 32] = e2 * inv + bi;
        cw2[base + btoff + (size_t)3 * 2 * 512 * 32] = e3 * inv + bi;
    }
}

// ---------------------------------------------------------------------------
// K3: sp[jh][b][k][i] = sum_{j in chunk jh} x*w*c.
// 512 blocks = 8 bt x 4 kt x 16 jh, XCD-aligned (XCD c owns jh {2c,2c+1}).
// Thread: 8b x 4k x float4 register tile (128 acc VGPRs; logical traffic
// 128 MB vs 192 MB for 4x4). ALL acc indices compile-time (rule #20: the
// rounds-4/5 110us regression was runtime-indexed acc -> scratch).
// Coalesced c staging; shfl_xor(32) pre-reduce; 2 static LDS rounds.
// ---------------------------------------------------------------------------
__global__ __launch_bounds__(256, 2) void k3_wsum(const float* __restrict__ x,
                                                  const float* __restrict__ w,
                                                  const float* __restrict__ cw2,
                                                  float* __restrict__ sp) {
    __shared__ float cl[JCW * 32];                     // 4 KB [jl][kk*8+bb]
    __shared__ __align__(16) float4 red[4 * 16 * 32];  // 32 KB [w][slot][iq]

    const int raw = blockIdx.x;                 // 0..511
    const int swz = (raw & 7) * 64 + (raw >> 3);
    const int kt = swz & 3, bt = (swz >> 2) & 7, jh = swz >> 5;
    const int j0 = jh * JCW, b0 = bt * 8, k0 = kt * 4;

    const int iq = threadIdx.x & 31;
    const int js = threadIdx.x >> 5;

    // coalesced c staging: 4 KB contiguous (one float4 per thread)
    ((float4*)cl)[threadIdx.x] =
        ((const float4*)(cw2 + ((size_t)(kt * 8 + bt) * 512 + j0) * 32))[threadIdx.x];
    __syncthreads();

    float4 acc[8][4];
#pragma unroll
    for (int bb = 0; bb < 8; ++bb)
#pragma unroll
        for (int kk = 0; kk < 4; ++kk) acc[bb][kk] = make_float4(0.f, 0.f, 0.f, 0.f);

#pragma unroll
    for (int it = 0; it < 4; ++it) {
        int j = j0 + js + it * 8;
        float4 xv[8], wv[4];
#pragma unroll
        for (int bb = 0; bb < 8; ++bb)
            xv[bb] = *(const float4*)(x + ((size_t)(b0 + bb) * J + j) * I + iq * 4);
#pragma unroll
        for (int kk = 0; kk < 4; ++kk)
            wv[kk] = *(const float4*)(w + ((size_t)(k0 + kk) * J + j) * I + iq * 4);
        const float* cj = cl + (js + it * 8) * 32;
#pragma unroll
        for (int kk = 0; kk < 4; ++kk) {
#pragma unroll
            for (int bb = 0; bb < 8; ++bb) {
                float c = cj[kk * 8 + bb];
                acc[bb][kk].x = fmaf(xv[bb].x * wv[kk].x, c, acc[bb][kk].x);
                acc[bb][kk].y = fmaf(xv[bb].y * wv[kk].y, c, acc[bb][kk].y);
                acc[bb][kk].z = fmaf(xv[bb].z * wv[kk].z, c, acc[bb][kk].z);
                acc[bb][kk].w = fmaf(xv[bb].w * wv[kk].w, c, acc[bb][kk].w);
            }
        }
    }

    // reduce across the two js-halves of each wave
#pragma unroll
    for (int bb = 0; bb < 8; ++bb)
#pragma unroll
        for (int kk = 0; kk < 4; ++kk) {
            acc[bb][kk].x += __shfl_xor(acc[bb][kk].x, 32, 64);
            acc[bb][kk].y += __shfl_xor(acc[bb][kk].y, 32, 64);
            acc[bb][kk].z += __shfl_xor(acc[bb][kk].z, 32, 64);
            acc[bb][kk].w += __shfl_xor(acc[bb][kk].w, 32, 64);
        }

    const int wv4 = threadIdx.x >> 6;
    // ---- round 0: bb 0..3 (all acc indices literal) ----
    if ((threadIdx.x & 32) == 0) {
#pragma unroll
        for (int bb = 0; bb < 4; ++bb)
#pragma unroll
            for (int kk = 0; kk < 4; ++kk)
                red[(wv4 * 16 + bb * 4 + kk) * 32 + iq] = acc[bb][kk];
    }
    __syncthreads();
    {
        int slot0 = threadIdx.x >> 5;  // 0..7
#pragma unroll
        for (int rep = 0; rep < 2; ++rep) {
            int slot = rep * 8 + slot0;
            float4 a = red[(0 * 16 + slot) * 32 + iq];
            float4 b = red[(1 * 16 + slot) * 32 + iq];
            float4 c = red[(2 * 16 + slot) * 32 + iq];
            float4 d = red[(3 * 16 + slot) * 32 + iq];
            float4 v = make_float4(a.x + b.x + c.x + d.x, a.y + b.y + c.y + d.y,
                                   a.z + b.z + c.z + d.z, a.w + b.w + c.w + d.w);
            int bb = slot >> 2, kk = slot & 3;
            *(float4*)(sp + (((size_t)jh * B + b0 + bb) * K + k0 + kk) * I + iq * 4) = v;
        }
    }
    __syncthreads();
    // ---- round 1: bb 4..7 ----
    if ((threadIdx.x & 32) == 0) {
#pragma unroll
        for (int bb = 0; bb < 4; ++bb)
#pragma unroll
            for (int kk = 0; kk < 4; ++kk)
                red[(wv4 * 16 + bb * 4 + kk) * 32 + iq] = acc[4 + bb][kk];
    }
    __syncthreads();
    {
        int slot0 = threadIdx.x >> 5;
#pragma unroll
        for (int rep = 0; rep < 2; ++rep) {
            int slot = rep * 8 + slot0;
            float4 a = red[(0 * 16 + slot) * 32 + iq];
            float4 b = red[(1 * 16 + slot) * 32 + iq];
            float4 c = red[(2 * 16 + slot) * 32 + iq];
            float4 d = red[(3 * 16 + slot) * 32 + iq];
            float4 v = make_float4(a.x + b.x + c.x + d.x, a.y + b.y + c.y + d.y,
                                   a.z + b.z + c.z + d.z, a.w + b.w + c.w + d.w);
            int bb = (slot >> 2) + 4, kk = slot & 3;
            *(float4*)(sp + (((size_t)jh * B + b0 + bb) * K + k0 + kk) * I + iq * 4) = v;
        }
    }
}

// ---------------------------------------------------------------------------
// K4: wave per (b,k): sum 16 partials, squash over i, write out. No LDS.
// ---------------------------------------------------------------------------
__global__ __launch_bounds__(256) void k4_squash(const float* __restrict__ sp,
                                                 float* __restrict__ out) {
    const int wv = threadIdx.x >> 6;
    const int lane = threadIdx.x & 63;
    const int bk = blockIdx.x * 4 + wv;       // 0..1023
    const int b = bk >> 4, k = bk & 15;

    float s0 = 0.f, s1 = 0.f;
#pragma unroll
    for (int p = 0; p < JC; ++p) {
        float2 v = *(const float2*)(sp + (((size_t)p * B + b) * K + k) * I + lane * 2);
        s0 += v.x; s1 += v.y;
    }
    float q = s0 * s0 + s1 * s1;
#pragma unroll
    for (int m = 32; m >= 1; m >>= 1) q += __shfl_xor(q, m, 64);

    float n = sqrtf(q);
    float factor = (1.0f - 1.0f / (expf(n) + EPSF)) / (n + EPSF);
    float2 o = make_float2(s0 * factor, s1 * factor);
    *(float2*)(out + ((size_t)b * K + k) * I + lane * 2) = o;
}

// ---------------------------------------------------------------------------
extern "C" void kernel_launch(void* const* d_in, const int* in_sizes, int n_in,
                              void* d_out, int out_size, void* d_ws, size_t ws_size,
                              hipStream_t stream) {
    const float* x    = (const float*)d_in[0];  // (B, J, I)
    const float* w    = (const float*)d_in[1];  // (K, J, I)
    const float* bias = (const float*)d_in[2];  // (K, J, 1)
    float* out = (float*)d_out;                 // (B, K, I)

    float* cw2 = (float*)d_ws;                  // 2 MB, blocked layout
    float* sp  = cw2 + (size_t)K * J * B;       // JC*B*K*I floats (8 MB)

    hipLaunchKernelGGL(k1_mfma,  dim3(512), dim3(256), 0, stream, x, w, bias, cw2);
    hipLaunchKernelGGL(k3_wsum,  dim3(512), dim3(256), 0, stream, x, w, cw2, sp);
    hipLaunchKernelGGL(k4_squash, dim3(256), dim3(256), 0, stream, sp, out);
}

// Round 8
// 27.813 us; speedup vs baseline: 1.8918x; 1.8918x over previous
//
#include <hip/hip_runtime.h>
#include <math.h>

#define B 64
#define K 16
#define J 512
#define I 128
#define SCALE 0.08838834764831845f /* 1/sqrt(128) */
#define EPSF 1e-20f
#define JC 32  /* j-chunks (sp partials) */
#define JCW 16 /* J / JC */

typedef __attribute__((ext_vector_type(8))) short short8;
typedef __attribute__((ext_vector_type(4))) float f32x4;

static __device__ __forceinline__ unsigned f2bf(float f) {
    union { float f; unsigned u; } v; v.f = f;
    return (v.u + 0x7FFFu + ((v.u >> 16) & 1u)) >> 16;  // RNE to bf16
}

// ---------------------------------------------------------------------------
// K1: logits via bf16 MFMA + softmax over batch + bias.
// 256 threads/block: 4 waves cooperatively stage x^2/w^2 (bf16, XOR-swizzle),
// wave 0 runs 16 MFMAs + in-register softmax. XCD-aligned j.
// Output blocked cw2[kt(4)][bt(8)][j(512)][kk(4)*8+bb(8)].
// ---------------------------------------------------------------------------
__global__ __launch_bounds__(256) void k1_mfma(const float* __restrict__ x,
                                               const float* __restrict__ w,
                                               const float* __restrict__ bias,
                                               float* __restrict__ cw2) {
    __shared__ __align__(16) char lds[80 * 256];  // lx[64][256] + lw[16][256]
    char* lx = lds;
    char* lw = lds + 64 * 256;

    const int raw = blockIdx.x;                  // 0..511
    const int j = (raw & 7) * 64 + (raw >> 3);   // XCD-aligned j
    const int tid = threadIdx.x;

#pragma unroll
    for (int r = 0; r < 8; ++r) {
        int item = tid + 256 * r;                // 0..2047
        int row = item >> 5, q = item & 31;
        float4 v = *(const float4*)(x + ((size_t)row * J + j) * I + q * 4);
        uint2 u;
        u.x = f2bf(v.x * v.x) | (f2bf(v.y * v.y) << 16);
        u.y = f2bf(v.z * v.z) | (f2bf(v.w * v.w) << 16);
        *(uint2*)(lx + row * 256 + ((q * 8) ^ ((row & 7) << 4))) = u;
    }
#pragma unroll
    for (int r = 0; r < 2; ++r) {
        int item = tid + 256 * r;                // 0..511
        int k = item >> 5, q = item & 31;
        float4 v = *(const float4*)(w + ((size_t)k * J + j) * I + q * 4);
        uint2 u;
        u.x = f2bf(v.x * v.x) | (f2bf(v.y * v.y) << 16);
        u.y = f2bf(v.z * v.z) | (f2bf(v.w * v.w) << 16);
        *(uint2*)(lw + k * 256 + ((q * 8) ^ ((k & 7) << 4))) = u;
    }
    __syncthreads();
    if (tid >= 64) return;

    const int g = tid >> 4, n = tid & 15;
    f32x4 acc[4];
#pragma unroll
    for (int t = 0; t < 4; ++t) acc[t] = (f32x4){0.f, 0.f, 0.f, 0.f};

#pragma unroll
    for (int s = 0; s < 4; ++s) {
        const int colb = s * 64 + g * 16;
        short8 af = *(const short8*)(lw + n * 256 + (colb ^ ((n & 7) << 4)));
#pragma unroll
        for (int t = 0; t < 4; ++t) {
            int row = t * 16 + n;
            short8 bf = *(const short8*)(lx + row * 256 + (colb ^ ((row & 7) << 4)));
            acc[t] = __builtin_amdgcn_mfma_f32_16x16x32_bf16(af, bf, acc[t], 0, 0, 0);
        }
    }

    // lane holds c_raw[m=g*4+r][b=t*16+n] in acc[t][r]
#pragma unroll
    for (int r = 0; r < 4; ++r) {
        float s0 = acc[0][r] * SCALE, s1 = acc[1][r] * SCALE;
        float s2 = acc[2][r] * SCALE, s3 = acc[3][r] * SCALE;
        float mx = fmaxf(fmaxf(s0, s1), fmaxf(s2, s3));
#pragma unroll
        for (int msk = 1; msk <= 8; msk <<= 1) mx = fmaxf(mx, __shfl_xor(mx, msk, 64));
        float e0 = expf(s0 - mx), e1 = expf(s1 - mx);
        float e2 = expf(s2 - mx), e3 = expf(s3 - mx);
        float sum = e0 + e1 + e2 + e3;
#pragma unroll
        for (int msk = 1; msk <= 8; msk <<= 1) sum += __shfl_xor(sum, msk, 64);
        float inv = 1.f / sum;
        float bi = bias[(g * 4 + r) * J + j];
        // cw2[kt=g][bt=t*2+(n>>3)][j][kk=r][bb=n&7]
        size_t base = (((size_t)g * 8) * 512 + j) * 32 + r * 8 + (n & 7);
        size_t btoff = (size_t)(n >> 3) * 512 * 32;
        cw2[base + btoff + (size_t)0 * 2 * 512 * 32] = e0 * inv + bi;
        cw2[base + btoff + (size_t)1 * 2 * 512 * 32] = e1 * inv + bi;
        cw2[base + btoff + (size_t)2 * 2 * 512 * 32] = e2 * inv + bi;
        cw2[base + btoff + (size_t)3 * 2 * 512 * 32] = e3 * inv + bi;
    }
}

// ---------------------------------------------------------------------------
// K3: sp[jh][b][k][i] = sum_{j in chunk jh} x*w*c.
// 1024 blocks = 8 bt x 4 kt x 32 jh, XCD-aligned (XCD c owns jh [4c,4c+4)
// = j in [64c,64c+64)). Thread: 8b x 4k x float2 tile -> acc = 64 VGPRs,
// total demand ~120 < 128 tier => 4 waves/SIMD, NO SPILL BY CONSTRUCTION
// (rounds 4/5/7 all died to acc spills: runtime indexing or >128 demand).
// Wave's 64 lanes cover all of i (float2); the 4 waves split the j-chunk.
// Epilogue: 2 static rounds (bb 0-3, 4-7) of LDS cross-wave reduction.
// ---------------------------------------------------------------------------
__global__ __launch_bounds__(256) void k3_wsum(const float* __restrict__ x,
                                               const float* __restrict__ w,
                                               const float* __restrict__ cw2,
                                               float* __restrict__ sp) {
    __shared__ float cl[JCW * 32];                      // 2 KB [jl][kk*8+bb]
    __shared__ __align__(16) float2 red[4][16][64];     // 32 KB

    const int raw = blockIdx.x;                 // 0..1023
    const int swz = (raw & 7) * 128 + (raw >> 3);
    const int kt = swz & 3, bt = (swz >> 2) & 7, jh = swz >> 5;  // jh 0..31
    const int j0 = jh * JCW, b0 = bt * 8, k0 = kt * 4;

    const int lane = threadIdx.x & 63;
    const int wvi  = threadIdx.x >> 6;          // 0..3

    if (threadIdx.x < 128)
        ((float4*)cl)[threadIdx.x] =
            ((const float4*)(cw2 + ((size_t)(kt * 8 + bt) * 512 + j0) * 32))[threadIdx.x];
    __syncthreads();

    float2 acc[8][4];
#pragma unroll
    for (int bb = 0; bb < 8; ++bb)
#pragma unroll
        for (int kk = 0; kk < 4; ++kk) acc[bb][kk] = make_float2(0.f, 0.f);

#pragma unroll
    for (int it = 0; it < 4; ++it) {
        const int j = j0 + wvi * 4 + it;
        float2 xv[8], wv[4];
#pragma unroll
        for (int bb = 0; bb < 8; ++bb)
            xv[bb] = *(const float2*)(x + ((size_t)(b0 + bb) * J + j) * I + lane * 2);
#pragma unroll
        for (int kk = 0; kk < 4; ++kk)
            wv[kk] = *(const float2*)(w + ((size_t)(k0 + kk) * J + j) * I + lane * 2);
        const float* cj = cl + (j - j0) * 32;
#pragma unroll
        for (int kk = 0; kk < 4; ++kk) {
            float4 cA = *(const float4*)(cj + kk * 8);      // bb 0..3
            float4 cB = *(const float4*)(cj + kk * 8 + 4);  // bb 4..7
            acc[0][kk].x = fmaf(xv[0].x * wv[kk].x, cA.x, acc[0][kk].x);
            acc[0][kk].y = fmaf(xv[0].y * wv[kk].y, cA.x, acc[0][kk].y);
            acc[1][kk].x = fmaf(xv[1].x * wv[kk].x, cA.y, acc[1][kk].x);
            acc[1][kk].y = fmaf(xv[1].y * wv[kk].y, cA.y, acc[1][kk].y);
            acc[2][kk].x = fmaf(xv[2].x * wv[kk].x, cA.z, acc[2][kk].x);
            acc[2][kk].y = fmaf(xv[2].y * wv[kk].y, cA.z, acc[2][kk].y);
            acc[3][kk].x = fmaf(xv[3].x * wv[kk].x, cA.w, acc[3][kk].x);
            acc[3][kk].y = fmaf(xv[3].y * wv[kk].y, cA.w, acc[3][kk].y);
            acc[4][kk].x = fmaf(xv[4].x * wv[kk].x, cB.x, acc[4][kk].x);
            acc[4][kk].y = fmaf(xv[4].y * wv[kk].y, cB.x, acc[4][kk].y);
            acc[5][kk].x = fmaf(xv[5].x * wv[kk].x, cB.y, acc[5][kk].x);
            acc[5][kk].y = fmaf(xv[5].y * wv[kk].y, cB.y, acc[5][kk].y);
            acc[6][kk].x = fmaf(xv[6].x * wv[kk].x, cB.z, acc[6][kk].x);
            acc[6][kk].y = fmaf(xv[6].y * wv[kk].y, cB.z, acc[6][kk].y);
            acc[7][kk].x = fmaf(xv[7].x * wv[kk].x, cB.w, acc[7][kk].x);
            acc[7][kk].y = fmaf(xv[7].y * wv[kk].y, cB.w, acc[7][kk].y);
        }
    }

    // ---- round 0: bb 0..3 (all acc indices literal) ----
#pragma unroll
    for (int bbl = 0; bbl < 4; ++bbl)
#pragma unroll
        for (int kk = 0; kk < 4; ++kk)
            red[wvi][bbl * 4 + kk][lane] = acc[bbl][kk];
    __syncthreads();
#pragma unroll
    for (int s = 0; s < 4; ++s) {
        int slot = wvi + 4 * s;                  // runtime: LDS/global only
        float2 a = red[0][slot][lane];
        float2 b = red[1][slot][lane];
        float2 c = red[2][slot][lane];
        float2 d = red[3][slot][lane];
        float2 v = make_float2(a.x + b.x + c.x + d.x, a.y + b.y + c.y + d.y);
        int bb = slot >> 2, kk = slot & 3;
        *(float2*)(sp + (((size_t)jh * B + b0 + bb) * K + k0 + kk) * I + lane * 2) = v;
    }
    __syncthreads();
    // ---- round 1: bb 4..7 ----
#pragma unroll
    for (int bbl = 0; bbl < 4; ++bbl)
#pragma unroll
        for (int kk = 0; kk < 4; ++kk)
            red[wvi][bbl * 4 + kk][lane] = acc[4 + bbl][kk];
    __syncthreads();
#pragma unroll
    for (int s = 0; s < 4; ++s) {
        int slot = wvi + 4 * s;
        float2 a = red[0][slot][lane];
        float2 b = red[1][slot][lane];
        float2 c = red[2][slot][lane];
        float2 d = red[3][slot][lane];
        float2 v = make_float2(a.x + b.x + c.x + d.x, a.y + b.y + c.y + d.y);
        int bb = (slot >> 2) + 4, kk = slot & 3;
        *(float2*)(sp + (((size_t)jh * B + b0 + bb) * K + k0 + kk) * I + lane * 2) = v;
    }
}

// ---------------------------------------------------------------------------
// K4: wave per (b,k): sum 32 partials, squash over i, write out. No LDS.
// ---------------------------------------------------------------------------
__global__ __launch_bounds__(256) void k4_squash(const float* __restrict__ sp,
                                                 float* __restrict__ out) {
    const int wv = threadIdx.x >> 6;
    const int lane = threadIdx.x & 63;
    const int bk = blockIdx.x * 4 + wv;       // 0..1023
    const int b = bk >> 4, k = bk & 15;

    float s0 = 0.f, s1 = 0.f;
#pragma unroll
    for (int p = 0; p < JC; ++p) {
        float2 v = *(const float2*)(sp + (((size_t)p * B + b) * K + k) * I + lane * 2);
        s0 += v.x; s1 += v.y;
    }
    float q = s0 * s0 + s1 * s1;
#pragma unroll
    for (int m = 32; m >= 1; m >>= 1) q += __shfl_xor(q, m, 64);

    float n = sqrtf(q);
    float factor = (1.0f - 1.0f / (expf(n) + EPSF)) / (n + EPSF);
    float2 o = make_float2(s0 * factor, s1 * factor);
    *(float2*)(out + ((size_t)b * K + k) * I + lane * 2) = o;
}

// ---------------------------------------------------------------------------
extern "C" void kernel_launch(void* const* d_in, const int* in_sizes, int n_in,
                              void* d_out, int out_size, void* d_ws, size_t ws_size,
                              hipStream_t stream) {
    const float* x    = (const float*)d_in[0];  // (B, J, I)
    const float* w    = (const float*)d_in[1];  // (K, J, I)
    const float* bias = (const float*)d_in[2];  // (K, J, 1)
    float* out = (float*)d_out;                 // (B, K, I)

    float* cw2 = (float*)d_ws;                  // 2 MB, blocked layout
    float* sp  = cw2 + (size_t)K * J * B;       // JC*B*K*I floats (16 MB)

    hipLaunchKernelGGL(k1_mfma,  dim3(512),  dim3(256), 0, stream, x, w, bias, cw2);
    hipLaunchKernelGGL(k3_wsum,  dim3(1024), dim3(256), 0, stream, x, w, cw2, sp);
    hipLaunchKernelGGL(k4_squash, dim3(256), dim3(256), 0, stream, sp, out);
}

// Round 9
// 24.833 us; speedup vs baseline: 2.1189x; 1.1200x over previous
//
#include <hip/hip_runtime.h>
#include <math.h>

#define B 64
#define K 16
#define J 512
#define I 128
#define SCALE 0.08838834764831845f /* 1/sqrt(128) */
#define EPSF 1e-20f
#define JC 32  /* j-chunks (sp partials) */
#define JCW 16 /* J / JC */

typedef __attribute__((ext_vector_type(8))) short short8;
typedef __attribute__((ext_vector_type(4))) float f32x4;
typedef __attribute__((ext_vector_type(2))) float f32x2;

static __device__ __forceinline__ unsigned f2bf(float f) {
    union { float f; unsigned u; } v; v.f = f;
    return (v.u + 0x7FFFu + ((v.u >> 16) & 1u)) >> 16;  // RNE to bf16
}

// ---------------------------------------------------------------------------
// K1: logits via bf16 MFMA + softmax over batch + bias.
// 256 threads/block: 4 waves cooperatively stage x^2/w^2 (bf16, XOR-swizzle),
// wave 0 runs 16 MFMAs + in-register softmax. XCD-aligned j.
// Output blocked cw2[kt(4)][bt(8)][j(512)][kk(4)*8+bb(8)] (normal stores:
// consumed by same-XCD k3 blocks, want it L2-resident).
// ---------------------------------------------------------------------------
__global__ __launch_bounds__(256) void k1_mfma(const float* __restrict__ x,
                                               const float* __restrict__ w,
                                               const float* __restrict__ bias,
                                               float* __restrict__ cw2) {
    __shared__ __align__(16) char lds[80 * 256];  // lx[64][256] + lw[16][256]
    char* lx = lds;
    char* lw = lds + 64 * 256;

    const int raw = blockIdx.x;                  // 0..511
    const int j = (raw & 7) * 64 + (raw >> 3);   // XCD-aligned j
    const int tid = threadIdx.x;

#pragma unroll
    for (int r = 0; r < 8; ++r) {
        int item = tid + 256 * r;                // 0..2047
        int row = item >> 5, q = item & 31;
        float4 v = *(const float4*)(x + ((size_t)row * J + j) * I + q * 4);
        uint2 u;
        u.x = f2bf(v.x * v.x) | (f2bf(v.y * v.y) << 16);
        u.y = f2bf(v.z * v.z) | (f2bf(v.w * v.w) << 16);
        *(uint2*)(lx + row * 256 + ((q * 8) ^ ((row & 7) << 4))) = u;
    }
#pragma unroll
    for (int r = 0; r < 2; ++r) {
        int item = tid + 256 * r;                // 0..511
        int k = item >> 5, q = item & 31;
        float4 v = *(const float4*)(w + ((size_t)k * J + j) * I + q * 4);
        uint2 u;
        u.x = f2bf(v.x * v.x) | (f2bf(v.y * v.y) << 16);
        u.y = f2bf(v.z * v.z) | (f2bf(v.w * v.w) << 16);
        *(uint2*)(lw + k * 256 + ((q * 8) ^ ((k & 7) << 4))) = u;
    }
    __syncthreads();
    if (tid >= 64) return;

    const int g = tid >> 4, n = tid & 15;
    f32x4 acc[4];
#pragma unroll
    for (int t = 0; t < 4; ++t) acc[t] = (f32x4){0.f, 0.f, 0.f, 0.f};

#pragma unroll
    for (int s = 0; s < 4; ++s) {
        const int colb = s * 64 + g * 16;
        short8 af = *(const short8*)(lw + n * 256 + (colb ^ ((n & 7) << 4)));
#pragma unroll
        for (int t = 0; t < 4; ++t) {
            int row = t * 16 + n;
            short8 bf = *(const short8*)(lx + row * 256 + (colb ^ ((row & 7) << 4)));
            acc[t] = __builtin_amdgcn_mfma_f32_16x16x32_bf16(af, bf, acc[t], 0, 0, 0);
        }
    }

    // lane holds c_raw[m=g*4+r][b=t*16+n] in acc[t][r]
#pragma unroll
    for (int r = 0; r < 4; ++r) {
        float s0 = acc[0][r] * SCALE, s1 = acc[1][r] * SCALE;
        float s2 = acc[2][r] * SCALE, s3 = acc[3][r] * SCALE;
        float mx = fmaxf(fmaxf(s0, s1), fmaxf(s2, s3));
#pragma unroll
        for (int msk = 1; msk <= 8; msk <<= 1) mx = fmaxf(mx, __shfl_xor(mx, msk, 64));
        float e0 = expf(s0 - mx), e1 = expf(s1 - mx);
        float e2 = expf(s2 - mx), e3 = expf(s3 - mx);
        float sum = e0 + e1 + e2 + e3;
#pragma unroll
        for (int msk = 1; msk <= 8; msk <<= 1) sum += __shfl_xor(sum, msk, 64);
        float inv = 1.f / sum;
        float bi = bias[(g * 4 + r) * J + j];
        // cw2[kt=g][bt=t*2+(n>>3)][j][kk=r][bb=n&7]
        size_t base = (((size_t)g * 8) * 512 + j) * 32 + r * 8 + (n & 7);
        size_t btoff = (size_t)(n >> 3) * 512 * 32;
        cw2[base + btoff + (size_t)0 * 2 * 512 * 32] = e0 * inv + bi;
        cw2[base + btoff + (size_t)1 * 2 * 512 * 32] = e1 * inv + bi;
        cw2[base + btoff + (size_t)2 * 2 * 512 * 32] = e2 * inv + bi;
        cw2[base + btoff + (size_t)3 * 2 * 512 * 32] = e3 * inv + bi;
    }
}

// ---------------------------------------------------------------------------
// K3: sp[jh][b][k][i] = sum_{j in chunk jh} x*w*c.
// 1024 blocks = 8 bt x 4 kt x 32 jh, XCD-aligned. 8b x 4k x float2 tile
// (acc 64 VGPRs, no spill). NEW: sp stores are NONTEMPORAL — sp is
// write-once dead data; with normal (write-allocate) stores the ~2 MB/XCD
// sp stream was evicting the 2.5 MB x/w reuse slice from the 4 MB L2,
// degrading the 96 MB of logical x/w re-reads to L3 refetches (theory for
// k3 being ~3x over its L2 model in rounds 6 and 8).
// ---------------------------------------------------------------------------
__global__ __launch_bounds__(256) void k3_wsum(const float* __restrict__ x,
                                               const float* __restrict__ w,
                                               const float* __restrict__ cw2,
                                               float* __restrict__ sp) {
    __shared__ float cl[JCW * 32];                      // 2 KB [jl][kk*8+bb]
    __shared__ __align__(16) float2 red[4][16][64];     // 32 KB

    const int raw = blockIdx.x;                 // 0..1023
    const int swz = (raw & 7) * 128 + (raw >> 3);
    const int kt = swz & 3, bt = (swz >> 2) & 7, jh = swz >> 5;  // jh 0..31
    const int j0 = jh * JCW, b0 = bt * 8, k0 = kt * 4;

    const int lane = threadIdx.x & 63;
    const int wvi  = threadIdx.x >> 6;          // 0..3

    if (threadIdx.x < 128)
        ((float4*)cl)[threadIdx.x] =
            ((const float4*)(cw2 + ((size_t)(kt * 8 + bt) * 512 + j0) * 32))[threadIdx.x];
    __syncthreads();

    float2 acc[8][4];
#pragma unroll
    for (int bb = 0; bb < 8; ++bb)
#pragma unroll
        for (int kk = 0; kk < 4; ++kk) acc[bb][kk] = make_float2(0.f, 0.f);

#pragma unroll
    for (int it = 0; it < 4; ++it) {
        const int j = j0 + wvi * 4 + it;
        float2 xv[8], wv[4];
#pragma unroll
        for (int bb = 0; bb < 8; ++bb)
            xv[bb] = *(const float2*)(x + ((size_t)(b0 + bb) * J + j) * I + lane * 2);
#pragma unroll
        for (int kk = 0; kk < 4; ++kk)
            wv[kk] = *(const float2*)(w + ((size_t)(k0 + kk) * J + j) * I + lane * 2);
        const float* cj = cl + (j - j0) * 32;
#pragma unroll
        for (int kk = 0; kk < 4; ++kk) {
            float4 cA = *(const float4*)(cj + kk * 8);      // bb 0..3
            float4 cB = *(const float4*)(cj + kk * 8 + 4);  // bb 4..7
            acc[0][kk].x = fmaf(xv[0].x * wv[kk].x, cA.x, acc[0][kk].x);
            acc[0][kk].y = fmaf(xv[0].y * wv[kk].y, cA.x, acc[0][kk].y);
            acc[1][kk].x = fmaf(xv[1].x * wv[kk].x, cA.y, acc[1][kk].x);
            acc[1][kk].y = fmaf(xv[1].y * wv[kk].y, cA.y, acc[1][kk].y);
            acc[2][kk].x = fmaf(xv[2].x * wv[kk].x, cA.z, acc[2][kk].x);
            acc[2][kk].y = fmaf(xv[2].y * wv[kk].y, cA.z, acc[2][kk].y);
            acc[3][kk].x = fmaf(xv[3].x * wv[kk].x, cA.w, acc[3][kk].x);
            acc[3][kk].y = fmaf(xv[3].y * wv[kk].y, cA.w, acc[3][kk].y);
            acc[4][kk].x = fmaf(xv[4].x * wv[kk].x, cB.x, acc[4][kk].x);
            acc[4][kk].y = fmaf(xv[4].y * wv[kk].y, cB.x, acc[4][kk].y);
            acc[5][kk].x = fmaf(xv[5].x * wv[kk].x, cB.y, acc[5][kk].x);
            acc[5][kk].y = fmaf(xv[5].y * wv[kk].y, cB.y, acc[5][kk].y);
            acc[6][kk].x = fmaf(xv[6].x * wv[kk].x, cB.z, acc[6][kk].x);
            acc[6][kk].y = fmaf(xv[6].y * wv[kk].y, cB.z, acc[6][kk].y);
            acc[7][kk].x = fmaf(xv[7].x * wv[kk].x, cB.w, acc[7][kk].x);
            acc[7][kk].y = fmaf(xv[7].y * wv[kk].y, cB.w, acc[7][kk].y);
        }
    }

    // ---- round 0: bb 0..3 (all acc indices literal) ----
#pragma unroll
    for (int bbl = 0; bbl < 4; ++bbl)
#pragma unroll
        for (int kk = 0; kk < 4; ++kk)
            red[wvi][bbl * 4 + kk][lane] = acc[bbl][kk];
    __syncthreads();
#pragma unroll
    for (int s = 0; s < 4; ++s) {
        int slot = wvi + 4 * s;                  // runtime: LDS/global only
        float2 a = red[0][slot][lane];
        float2 b = red[1][slot][lane];
        float2 c = red[2][slot][lane];
        float2 d = red[3][slot][lane];
        f32x2 v = {a.x + b.x + c.x + d.x, a.y + b.y + c.y + d.y};
        int bb = slot >> 2, kk = slot & 3;
        __builtin_nontemporal_store(
            v, (f32x2*)(sp + (((size_t)jh * B + b0 + bb) * K + k0 + kk) * I + lane * 2));
    }
    __syncthreads();
    // ---- round 1: bb 4..7 ----
#pragma unroll
    for (int bbl = 0; bbl < 4; ++bbl)
#pragma unroll
        for (int kk = 0; kk < 4; ++kk)
            red[wvi][bbl * 4 + kk][lane] = acc[4 + bbl][kk];
    __syncthreads();
#pragma unroll
    for (int s = 0; s < 4; ++s) {
        int slot = wvi + 4 * s;
        float2 a = red[0][slot][lane];
        float2 b = red[1][slot][lane];
        float2 c = red[2][slot][lane];
        float2 d = red[3][slot][lane];
        f32x2 v = {a.x + b.x + c.x + d.x, a.y + b.y + c.y + d.y};
        int bb = (slot >> 2) + 4, kk = slot & 3;
        __builtin_nontemporal_store(
            v, (f32x2*)(sp + (((size_t)jh * B + b0 + bb) * K + k0 + kk) * I + lane * 2));
    }
}

// ---------------------------------------------------------------------------
// K4: wave per (b,k): sum 32 partials, squash over i, write out.
// sp reads + out writes nontemporal (read-once / write-once; keep L2 clean).
// ---------------------------------------------------------------------------
__global__ __launch_bounds__(256) void k4_squash(const float* __restrict__ sp,
                                                 float* __restrict__ out) {
    const int wv = threadIdx.x >> 6;
    const int lane = threadIdx.x & 63;
    const int bk = blockIdx.x * 4 + wv;       // 0..1023
    const int b = bk >> 4, k = bk & 15;

    float s0 = 0.f, s1 = 0.f;
#pragma unroll
    for (int p = 0; p < JC; ++p) {
        f32x2 v = __builtin_nontemporal_load(
            (const f32x2*)(sp + (((size_t)p * B + b) * K + k) * I + lane * 2));
        s0 += v.x; s1 += v.y;
    }
    float q = s0 * s0 + s1 * s1;
#pragma unroll
    for (int m = 32; m >= 1; m >>= 1) q += __shfl_xor(q, m, 64);

    float n = sqrtf(q);
    float factor = (1.0f - 1.0f / (expf(n) + EPSF)) / (n + EPSF);
    f32x2 o = {s0 * factor, s1 * factor};
    __builtin_nontemporal_store(
        o, (f32x2*)(out + ((size_t)b * K + k) * I + lane * 2));
}

// ---------------------------------------------------------------------------
extern "C" void kernel_launch(void* const* d_in, const int* in_sizes, int n_in,
                              void* d_out, int out_size, void* d_ws, size_t ws_size,
                              hipStream_t stream) {
    const float* x    = (const float*)d_in[0];  // (B, J, I)
    const float* w    = (const float*)d_in[1];  // (K, J, I)
    const float* bias = (const float*)d_in[2];  // (K, J, 1)
    float* out = (float*)d_out;                 // (B, K, I)

    float* cw2 = (float*)d_ws;                  // 2 MB, blocked layout
    float* sp  = cw2 + (size_t)K * J * B;       // JC*B*K*I floats (16 MB)

    hipLaunchKernelGGL(k1_mfma,  dim3(512),  dim3(256), 0, stream, x, w, bias, cw2);
    hipLaunchKernelGGL(k3_wsum,  dim3(1024), dim3(256), 0, stream, x, w, cw2, sp);
    hipLaunchKernelGGL(k4_squash, dim3(256), dim3(256), 0, stream, sp, out);
}

// Round 10
// 24.691 us; speedup vs baseline: 2.1311x; 1.0058x over previous
//
#include <hip/hip_runtime.h>
#include <math.h>

#define B 64
#define K 16
#define J 512
#define I 128
#define SCALE 0.08838834764831845f /* 1/sqrt(128) */
#define EPSF 1e-20f
#define JC 32  /* j-chunks (sp partials) */
#define JCW 16 /* J / JC */

typedef __attribute__((ext_vector_type(8))) short short8;
typedef __attribute__((ext_vector_type(4))) float f32x4;
typedef __attribute__((ext_vector_type(2))) float f32x2;
typedef __attribute__((ext_vector_type(2))) _Float16 f16x2;
typedef __attribute__((ext_vector_type(4))) _Float16 f16x4;

static __device__ __forceinline__ unsigned f2bf(float f) {
    union { float f; unsigned u; } v; v.f = f;
    return (v.u + 0x7FFFu + ((v.u >> 16) & 1u)) >> 16;  // RNE to bf16
}

// ---------------------------------------------------------------------------
// K1: logits via bf16 MFMA + softmax over batch + bias, AND emit f16 raw
// copies of x,w in XCD-blocked contiguous layout:
//   xh[jc(8)][b(64)][jl(64)][i(128)], wh[jc(8)][k(16)][jl(64)][i(128)]
// Purpose: x's b-stride is exactly 256 KB -> all 64 b-extents of a k3 block
// alias the same L2 sets (set bits << bit18), so the "2 MB slice" could
// never be L2-resident (theory for k3 stuck at ~13us = L3/HBM speed).
// The blocked copy is contiguous per XCD chunk (1.25 MB) -> no aliasing.
// ---------------------------------------------------------------------------
__global__ __launch_bounds__(256) void k1_mfma(const float* __restrict__ x,
                                               const float* __restrict__ w,
                                               const float* __restrict__ bias,
                                               float* __restrict__ cw2,
                                               _Float16* __restrict__ xh,
                                               _Float16* __restrict__ wh) {
    __shared__ __align__(16) char lds[80 * 256];  // lx[64][256] + lw[16][256]
    char* lx = lds;
    char* lw = lds + 64 * 256;

    const int raw = blockIdx.x;                  // 0..511
    const int j = (raw & 7) * 64 + (raw >> 3);   // XCD-aligned j
    const int jc2 = raw & 7;                     // j >> 6
    const int jl = raw >> 3;                     // j & 63
    const int tid = threadIdx.x;

#pragma unroll
    for (int r = 0; r < 8; ++r) {
        int item = tid + 256 * r;                // 0..2047
        int row = item >> 5, q = item & 31;
        float4 v = *(const float4*)(x + ((size_t)row * J + j) * I + q * 4);
        // f16 raw copy (blocked)
        f16x4 h = {(_Float16)v.x, (_Float16)v.y, (_Float16)v.z, (_Float16)v.w};
        *(f16x4*)(xh + (((size_t)jc2 * B + row) * 64 + jl) * I + q * 4) = h;
        // bf16 square for MFMA
        uint2 u;
        u.x = f2bf(v.x * v.x) | (f2bf(v.y * v.y) << 16);
        u.y = f2bf(v.z * v.z) | (f2bf(v.w * v.w) << 16);
        *(uint2*)(lx + row * 256 + ((q * 8) ^ ((row & 7) << 4))) = u;
    }
#pragma unroll
    for (int r = 0; r < 2; ++r) {
        int item = tid + 256 * r;                // 0..511
        int k = item >> 5, q = item & 31;
        float4 v = *(const float4*)(w + ((size_t)k * J + j) * I + q * 4);
        f16x4 h = {(_Float16)v.x, (_Float16)v.y, (_Float16)v.z, (_Float16)v.w};
        *(f16x4*)(wh + (((size_t)jc2 * K + k) * 64 + jl) * I + q * 4) = h;
        uint2 u;
        u.x = f2bf(v.x * v.x) | (f2bf(v.y * v.y) << 16);
        u.y = f2bf(v.z * v.z) | (f2bf(v.w * v.w) << 16);
        *(uint2*)(lw + k * 256 + ((q * 8) ^ ((k & 7) << 4))) = u;
    }
    __syncthreads();
    if (tid >= 64) return;

    const int g = tid >> 4, n = tid & 15;
    f32x4 acc[4];
#pragma unroll
    for (int t = 0; t < 4; ++t) acc[t] = (f32x4){0.f, 0.f, 0.f, 0.f};

#pragma unroll
    for (int s = 0; s < 4; ++s) {
        const int colb = s * 64 + g * 16;
        short8 af = *(const short8*)(lw + n * 256 + (colb ^ ((n & 7) << 4)));
#pragma unroll
        for (int t = 0; t < 4; ++t) {
            int row = t * 16 + n;
            short8 bf = *(const short8*)(lx + row * 256 + (colb ^ ((row & 7) << 4)));
            acc[t] = __builtin_amdgcn_mfma_f32_16x16x32_bf16(af, bf, acc[t], 0, 0, 0);
        }
    }

    // lane holds c_raw[m=g*4+r][b=t*16+n] in acc[t][r]
#pragma unroll
    for (int r = 0; r < 4; ++r) {
        float s0 = acc[0][r] * SCALE, s1 = acc[1][r] * SCALE;
        float s2 = acc[2][r] * SCALE, s3 = acc[3][r] * SCALE;
        float mx = fmaxf(fmaxf(s0, s1), fmaxf(s2, s3));
#pragma unroll
        for (int msk = 1; msk <= 8; msk <<= 1) mx = fmaxf(mx, __shfl_xor(mx, msk, 64));
        float e0 = expf(s0 - mx), e1 = expf(s1 - mx);
        float e2 = expf(s2 - mx), e3 = expf(s3 - mx);
        float sum = e0 + e1 + e2 + e3;
#pragma unroll
        for (int msk = 1; msk <= 8; msk <<= 1) sum += __shfl_xor(sum, msk, 64);
        float inv = 1.f / sum;
        float bi = bias[(g * 4 + r) * J + j];
        // cw2[kt=g][bt=t*2+(n>>3)][j][kk=r][bb=n&7]
        size_t base = (((size_t)g * 8) * 512 + j) * 32 + r * 8 + (n & 7);
        size_t btoff = (size_t)(n >> 3) * 512 * 32;
        cw2[base + btoff + (size_t)0 * 2 * 512 * 32] = e0 * inv + bi;
        cw2[base + btoff + (size_t)1 * 2 * 512 * 32] = e1 * inv + bi;
        cw2[base + btoff + (size_t)2 * 2 * 512 * 32] = e2 * inv + bi;
        cw2[base + btoff + (size_t)3 * 2 * 512 * 32] = e3 * inv + bi;
    }
}

// ---------------------------------------------------------------------------
// K3: sp[jh][b][k][i] = sum_{j in chunk jh} x*w*c, reading the f16 BLOCKED
// copies (contiguous 1.25 MB per XCD -> L2-resident, no set aliasing;
// half the bytes of f32). 1024 blocks = 8 bt x 4 kt x 32 jh, XCD-aligned.
// 8b x 4k x float2 acc tile (64 VGPRs, all indices compile-time).
// sp stores nontemporal (write-once).
// ---------------------------------------------------------------------------
__global__ __launch_bounds__(256) void k3_wsum(const _Float16* __restrict__ xh,
                                               const _Float16* __restrict__ wh,
                                               const float* __restrict__ cw2,
                                               float* __restrict__ sp) {
    __shared__ float cl[JCW * 32];                      // 2 KB [jl][kk*8+bb]
    __shared__ __align__(16) float2 red[4][16][64];     // 32 KB

    const int raw = blockIdx.x;                 // 0..1023
    const int swz = (raw & 7) * 128 + (raw >> 3);
    const int kt = swz & 3, bt = (swz >> 2) & 7, jh = swz >> 5;  // jh 0..31
    const int j0 = jh * JCW, b0 = bt * 8, k0 = kt * 4;
    const int jc2 = jh >> 2;                    // XCD chunk 0..7
    const int jlb = (jh & 3) * JCW;             // chunk-local base 0..48

    const int lane = threadIdx.x & 63;
    const int wvi  = threadIdx.x >> 6;          // 0..3

    if (threadIdx.x < 128)
        ((float4*)cl)[threadIdx.x] =
            ((const float4*)(cw2 + ((size_t)(kt * 8 + bt) * 512 + j0) * 32))[threadIdx.x];
    __syncthreads();

    float2 acc[8][4];
#pragma unroll
    for (int bb = 0; bb < 8; ++bb)
#pragma unroll
        for (int kk = 0; kk < 4; ++kk) acc[bb][kk] = make_float2(0.f, 0.f);

#pragma unroll
    for (int it = 0; it < 4; ++it) {
        const int jli = wvi * 4 + it;           // 0..15 within this jh chunk
        const int jl = jlb + jli;               // 0..63 within XCD chunk
        float2 xv[8], wv[4];
#pragma unroll
        for (int bb = 0; bb < 8; ++bb) {
            f16x2 h = *(const f16x2*)(xh + (((size_t)jc2 * B + b0 + bb) * 64 + jl) * I + lane * 2);
            xv[bb] = make_float2((float)h.x, (float)h.y);
        }
#pragma unroll
        for (int kk = 0; kk < 4; ++kk) {
            f16x2 h = *(const f16x2*)(wh + (((size_t)jc2 * K + k0 + kk) * 64 + jl) * I + lane * 2);
            wv[kk] = make_float2((float)h.x, (float)h.y);
        }
        const float* cj = cl + jli * 32;
#pragma unroll
        for (int kk = 0; kk < 4; ++kk) {
            float4 cA = *(const float4*)(cj + kk * 8);      // bb 0..3
            float4 cB = *(const float4*)(cj + kk * 8 + 4);  // bb 4..7
            acc[0][kk].x = fmaf(xv[0].x * wv[kk].x, cA.x, acc[0][kk].x);
            acc[0][kk].y = fmaf(xv[0].y * wv[kk].y, cA.x, acc[0][kk].y);
            acc[1][kk].x = fmaf(xv[1].x * wv[kk].x, cA.y, acc[1][kk].x);
            acc[1][kk].y = fmaf(xv[1].y * wv[kk].y, cA.y, acc[1][kk].y);
            acc[2][kk].x = fmaf(xv[2].x * wv[kk].x, cA.z, acc[2][kk].x);
            acc[2][kk].y = fmaf(xv[2].y * wv[kk].y, cA.z, acc[2][kk].y);
            acc[3][kk].x = fmaf(xv[3].x * wv[kk].x, cA.w, acc[3][kk].x);
            acc[3][kk].y = fmaf(xv[3].y * wv[kk].y, cA.w, acc[3][kk].y);
            acc[4][kk].x = fmaf(xv[4].x * wv[kk].x, cB.x, acc[4][kk].x);
            acc[4][kk].y = fmaf(xv[4].y * wv[kk].y, cB.x, acc[4][kk].y);
            acc[5][kk].x = fmaf(xv[5].x * wv[kk].x, cB.y, acc[5][kk].x);
            acc[5][kk].y = fmaf(xv[5].y * wv[kk].y, cB.y, acc[5][kk].y);
            acc[6][kk].x = fmaf(xv[6].x * wv[kk].x, cB.z, acc[6][kk].x);
            acc[6][kk].y = fmaf(xv[6].y * wv[kk].y, cB.z, acc[6][kk].y);
            acc[7][kk].x = fmaf(xv[7].x * wv[kk].x, cB.w, acc[7][kk].x);
            acc[7][kk].y = fmaf(xv[7].y * wv[kk].y, cB.w, acc[7][kk].y);
        }
    }

    // ---- round 0: bb 0..3 (all acc indices literal) ----
#pragma unroll
    for (int bbl = 0; bbl < 4; ++bbl)
#pragma unroll
        for (int kk = 0; kk < 4; ++kk)
            red[wvi][bbl * 4 + kk][lane] = acc[bbl][kk];
    __syncthreads();
#pragma unroll
    for (int s = 0; s < 4; ++s) {
        int slot = wvi + 4 * s;                  // runtime: LDS/global only
        float2 a = red[0][slot][lane];
        float2 b = red[1][slot][lane];
        float2 c = red[2][slot][lane];
        float2 d = red[3][slot][lane];
        f32x2 v = {a.x + b.x + c.x + d.x, a.y + b.y + c.y + d.y};
        int bb = slot >> 2, kk = slot & 3;
        __builtin_nontemporal_store(
            v, (f32x2*)(sp + (((size_t)jh * B + b0 + bb) * K + k0 + kk) * I + lane * 2));
    }
    __syncthreads();
    // ---- round 1: bb 4..7 ----
#pragma unroll
    for (int bbl = 0; bbl < 4; ++bbl)
#pragma unroll
        for (int kk = 0; kk < 4; ++kk)
            red[wvi][bbl * 4 + kk][lane] = acc[4 + bbl][kk];
    __syncthreads();
#pragma unroll
    for (int s = 0; s < 4; ++s) {
        int slot = wvi + 4 * s;
        float2 a = red[0][slot][lane];
        float2 b = red[1][slot][lane];
        float2 c = red[2][slot][lane];
        float2 d = red[3][slot][lane];
        f32x2 v = {a.x + b.x + c.x + d.x, a.y + b.y + c.y + d.y};
        int bb = (slot >> 2) + 4, kk = slot & 3;
        __builtin_nontemporal_store(
            v, (f32x2*)(sp + (((size_t)jh * B + b0 + bb) * K + k0 + kk) * I + lane * 2));
    }
}

// ---------------------------------------------------------------------------
// K4: wave per (b,k): sum 32 partials, squash over i, write out.
// sp reads + out writes nontemporal.
// ---------------------------------------------------------------------------
__global__ __launch_bounds__(256) void k4_squash(const float* __restrict__ sp,
                                                 float* __restrict__ out) {
    const int wv = threadIdx.x >> 6;
    const int lane = threadIdx.x & 63;
    const int bk = blockIdx.x * 4 + wv;       // 0..1023
    const int b = bk >> 4, k = bk & 15;

    float s0 = 0.f, s1 = 0.f;
#pragma unroll
    for (int p = 0; p < JC; ++p) {
        f32x2 v = __builtin_nontemporal_load(
            (const f32x2*)(sp + (((size_t)p * B + b) * K + k) * I + lane * 2));
        s0 += v.x; s1 += v.y;
    }
    float q = s0 * s0 + s1 * s1;
#pragma unroll
    for (int m = 32; m >= 1; m >>= 1) q += __shfl_xor(q, m, 64);

    float n = sqrtf(q);
    float factor = (1.0f - 1.0f / (expf(n) + EPSF)) / (n + EPSF);
    f32x2 o = {s0 * factor, s1 * factor};
    __builtin_nontemporal_store(
        o, (f32x2*)(out + ((size_t)b * K + k) * I + lane * 2));
}

// ---------------------------------------------------------------------------
extern "C" void kernel_launch(void* const* d_in, const int* in_sizes, int n_in,
                              void* d_out, int out_size, void* d_ws, size_t ws_size,
                              hipStream_t stream) {
    const float* x    = (const float*)d_in[0];  // (B, J, I)
    const float* w    = (const float*)d_in[1];  // (K, J, I)
    const float* bias = (const float*)d_in[2];  // (K, J, 1)
    float* out = (float*)d_out;                 // (B, K, I)

    float* cw2 = (float*)d_ws;                        // 2 MB, blocked c
    float* sp  = cw2 + (size_t)K * J * B;             // 16 MB partials
    _Float16* xh = (_Float16*)(sp + (size_t)JC * B * K * I);  // 8 MB f16 x
    _Float16* wh = xh + (size_t)B * J * I;                    // 2 MB f16 w

    hipLaunchKernelGGL(k1_mfma,  dim3(512),  dim3(256), 0, stream,
                       x, w, bias, cw2, xh, wh);
    hipLaunchKernelGGL(k3_wsum,  dim3(1024), dim3(256), 0, stream,
                       xh, wh, cw2, sp);
    hipLaunchKernelGGL(k4_squash, dim3(256), dim3(256), 0, stream, sp, out);
}